// Round 1
// baseline (1498.388 us; speedup 1.0000x reference)
//
#include <hip/hip_runtime.h>
#include <math.h>

#define N_NODES 50000
#define N_EDGES 400000
#define DIM 512
#define NLAYER 3
#define INNER 2048
#define BN_EPS 1e-5f

typedef unsigned short u16;
typedef unsigned int u32;

typedef __attribute__((ext_vector_type(8))) short bf16x8;
typedef __attribute__((ext_vector_type(4))) float f32x4;

__device__ __forceinline__ u16 f2bf(float f) {
  union { float f; u32 u; } v; v.f = f;
  u32 u = v.u;
  u32 r = (u + 0x7FFFu + ((u >> 16) & 1u)) >> 16;  // RNE
  return (u16)r;
}
__device__ __forceinline__ float bf2f(u16 h) {
  union { u32 u; float f; } v; v.u = ((u32)h) << 16; return v.f;
}

// ---------------- graph prep ----------------

__global__ void k_deg(const int* __restrict__ ei, int* __restrict__ deg) {
  int e = blockIdx.x * blockDim.x + threadIdx.x;
  if (e < N_EDGES) atomicAdd(&deg[ei[N_EDGES + e]], 1);
}

__global__ void k_dinv(const int* __restrict__ deg, float* __restrict__ dinv) {
  int i = blockIdx.x * blockDim.x + threadIdx.x;
  if (i < N_NODES) dinv[i] = rsqrtf((float)(deg[i] + 1));
}

__global__ __launch_bounds__(1024) void k_scan(const int* __restrict__ deg,
                                               int* __restrict__ offs, int n) {
  __shared__ int wsum[16];
  __shared__ int carry;
  int tid = threadIdx.x;
  int lane = tid & 63, wv = tid >> 6;
  if (tid == 0) carry = 0;
  __syncthreads();
  for (int base = 0; base < n; base += 1024) {
    int i = base + tid;
    int v = (i < n) ? deg[i] : 0;
    int x = v;
#pragma unroll
    for (int d = 1; d < 64; d <<= 1) {
      int y = __shfl_up(x, d, 64);
      if (lane >= d) x += y;
    }
    if (lane == 63) wsum[wv] = x;
    __syncthreads();
    if (wv == 0) {
      int w = (lane < 16) ? wsum[lane] : 0;
#pragma unroll
      for (int d = 1; d < 16; d <<= 1) {
        int y = __shfl_up(w, d, 64);
        if (lane >= d) w += y;
      }
      if (lane < 16) wsum[lane] = w;
    }
    __syncthreads();
    int prev = carry + (wv ? wsum[wv - 1] : 0);
    if (i < n) offs[i] = prev + x - v;
    int total = wsum[15];
    __syncthreads();
    if (tid == 0) carry += total;
    __syncthreads();
  }
  if (tid == 0) offs[n] = carry;
}

__global__ void k_fill(const int* __restrict__ ei, const int* __restrict__ offs,
                       int* __restrict__ cursor, const float* __restrict__ dinv,
                       int* __restrict__ csr_src, float* __restrict__ csr_norm) {
  int e = blockIdx.x * blockDim.x + threadIdx.x;
  if (e >= N_EDGES) return;
  int s = ei[e];
  int d = ei[N_EDGES + e];
  int p = atomicAdd(&cursor[d], 1);
  int idx = offs[d] + p;
  csr_src[idx] = s;
  csr_norm[idx] = dinv[s] * dinv[d];
}

// fp32 -> bf16 elementwise (4 elems/thread)
__global__ void k_convert(const float* __restrict__ src, u16* __restrict__ dst, int n4) {
  int i = blockIdx.x * blockDim.x + threadIdx.x;
  if (i >= n4) return;
  float4 v = ((const float4*)src)[i];
  uint2 o;
  o.x = (u32)f2bf(v.x) | ((u32)f2bf(v.y) << 16);
  o.y = (u32)f2bf(v.z) | ((u32)f2bf(v.w) << 16);
  ((uint2*)dst)[i] = o;
}

// W [K,512] fp32 -> WT [512,K] bf16, optional per-k scale
__global__ void k_transpose_scale(const float* __restrict__ W, const float* __restrict__ scale,
                                  u16* __restrict__ WT, int K) {
  int t = blockIdx.x * blockDim.x + threadIdx.x;
  if (t >= K * DIM) return;
  int k = t >> 9;
  int j = t & 511;
  float v = W[t];
  if (scale) v *= scale[k];
  WT[(size_t)j * K + k] = f2bf(v);
}

// ---------------- GEMM: C[M,512] = A[M,K] @ Bt[512,K]^T (+bias), bf16 in / fp32 out
#define BM 128
#define BN 128
#define BK 32
#define LDK 40

__global__ __launch_bounds__(256) void gemm_bt(
    const u16* __restrict__ A0, const u16* __restrict__ A1,
    const u16* __restrict__ A2, const u16* __restrict__ A3,
    const u16* __restrict__ Bt, const float* __restrict__ bias,
    float* __restrict__ C, int M, int K) {
  __shared__ __align__(16) u16 As[BM * LDK];
  __shared__ __align__(16) u16 Bs[BN * LDK];
  int tid = threadIdx.x;
  int m0 = blockIdx.x * BM;
  int n0 = blockIdx.y * BN;
  int wave = tid >> 6, lane = tid & 63;
  int wm = (wave & 1) * 64, wn = (wave >> 1) * 64;
  int lr = lane & 15;  // row within 16 (m for A / n for B / col for C)
  int lq = lane >> 4;  // quad

  f32x4 acc[4][4];
#pragma unroll
  for (int i = 0; i < 4; i++)
#pragma unroll
    for (int j = 0; j < 4; j++) acc[i][j] = (f32x4){0.f, 0.f, 0.f, 0.f};

  for (int k0 = 0; k0 < K; k0 += BK) {
    int b = k0 >> 9;
    int kcol = k0 & 511;
    const u16* Abase = (b == 0) ? A0 : (b == 1) ? A1 : (b == 2) ? A2 : A3;
    // stage A: 128 rows x 32 k, 16B per chunk, 512 chunks of 8 bf16 / 256 thr = 2 each
#pragma unroll
    for (int c = tid; c < BM * 4; c += 256) {
      int row = c >> 2, kc = (c & 3) * 8;
      int gr = m0 + row;
      uint4 v = {0u, 0u, 0u, 0u};
      if (gr < M) v = *(const uint4*)(Abase + (size_t)gr * DIM + kcol + kc);
      *(uint4*)(&As[row * LDK + kc]) = v;
    }
#pragma unroll
    for (int c = tid; c < BN * 4; c += 256) {
      int row = c >> 2, kc = (c & 3) * 8;
      uint4 v = *(const uint4*)(Bt + (size_t)(n0 + row) * K + k0 + kc);
      *(uint4*)(&Bs[row * LDK + kc]) = v;
    }
    __syncthreads();
    bf16x8 af[4], bfr[4];
#pragma unroll
    for (int i = 0; i < 4; i++)
      af[i] = *(const bf16x8*)(&As[(wm + i * 16 + lr) * LDK + lq * 8]);
#pragma unroll
    for (int j = 0; j < 4; j++)
      bfr[j] = *(const bf16x8*)(&Bs[(wn + j * 16 + lr) * LDK + lq * 8]);
#pragma unroll
    for (int i = 0; i < 4; i++)
#pragma unroll
      for (int j = 0; j < 4; j++)
        acc[i][j] = __builtin_amdgcn_mfma_f32_16x16x32_bf16(af[i], bfr[j], acc[i][j], 0, 0, 0);
    __syncthreads();
  }
  // epilogue: D[row][col], col = lane&15, row = quad*4 + reg
#pragma unroll
  for (int i = 0; i < 4; i++) {
    int row_b = m0 + wm + i * 16 + lq * 4;
#pragma unroll
    for (int j = 0; j < 4; j++) {
      int col = n0 + wn + j * 16 + lr;
      float bv = bias ? bias[col] : 0.f;
#pragma unroll
      for (int r = 0; r < 4; r++) {
        int row = row_b + r;
        if (row < M) C[(size_t)row * DIM + col] = acc[i][j][r] + bv;
      }
    }
  }
}

// ---------------- aggregation: per dst node, no atomics ----------------
__global__ __launch_bounds__(128) void k_aggregate(
    const float* __restrict__ hp, const int* __restrict__ offs,
    const int* __restrict__ csr_src, const float* __restrict__ csr_norm,
    const float* __restrict__ dinv, const float* __restrict__ b,
    u16* __restrict__ hb_out) {
  int v = blockIdx.x;
  int c4 = threadIdx.x * 4;
  float4 acc = {0.f, 0.f, 0.f, 0.f};
  int e0 = offs[v], e1 = offs[v + 1];
  for (int e = e0; e < e1; e++) {
    int s = csr_src[e];
    float w = csr_norm[e];
    float4 hv = *(const float4*)(hp + (size_t)s * DIM + c4);
    acc.x += w * hv.x; acc.y += w * hv.y; acc.z += w * hv.z; acc.w += w * hv.w;
  }
  float di = dinv[v];
  float w2 = di * di;
  float4 hv = *(const float4*)(hp + (size_t)v * DIM + c4);
  float4 bb = *(const float4*)(b + c4);
  acc.x += w2 * hv.x + bb.x;
  acc.y += w2 * hv.y + bb.y;
  acc.z += w2 * hv.z + bb.z;
  acc.w += w2 * hv.w + bb.w;
  // exact GELU
  acc.x = 0.5f * acc.x * (1.f + erff(acc.x * 0.70710678118654752f));
  acc.y = 0.5f * acc.y * (1.f + erff(acc.y * 0.70710678118654752f));
  acc.z = 0.5f * acc.z * (1.f + erff(acc.z * 0.70710678118654752f));
  acc.w = 0.5f * acc.w * (1.f + erff(acc.w * 0.70710678118654752f));
  uint2 o;
  o.x = (u32)f2bf(acc.x) | ((u32)f2bf(acc.y) << 16);
  o.y = (u32)f2bf(acc.z) | ((u32)f2bf(acc.w) << 16);
  *(uint2*)(hb_out + (size_t)v * DIM + c4) = o;
}

// ---------------- BN stats ----------------
__global__ void k_bn_stats(const u16* __restrict__ b0, const u16* __restrict__ b1,
                           const u16* __restrict__ b2, const u16* __restrict__ b3,
                           float* __restrict__ sums, float* __restrict__ sumsq,
                           int rows_per) {
  const u16* buf = (blockIdx.x == 0) ? b0 : (blockIdx.x == 1) ? b1 : (blockIdx.x == 2) ? b2 : b3;
  int c = threadIdx.x * 2;  // local col pair within buffer
  int col = blockIdx.x * DIM + c;
  int r0 = blockIdx.y * rows_per;
  int r1 = min(N_NODES, r0 + rows_per);
  float s0 = 0.f, ss0 = 0.f, s1 = 0.f, ss1 = 0.f;
  for (int r = r0; r < r1; r++) {
    u32 u = *(const u32*)(buf + (size_t)r * DIM + c);
    float x0 = bf2f((u16)(u & 0xffffu));
    float x1 = bf2f((u16)(u >> 16));
    s0 += x0; ss0 += x0 * x0;
    s1 += x1; ss1 += x1 * x1;
  }
  atomicAdd(&sums[col], s0);
  atomicAdd(&sumsq[col], ss0);
  atomicAdd(&sums[col + 1], s1);
  atomicAdd(&sumsq[col + 1], ss1);
}

__global__ void k_bn_finalize(const float* __restrict__ sums, const float* __restrict__ sumsq,
                              const float* __restrict__ gamma, const float* __restrict__ beta,
                              float* __restrict__ scale, float* __restrict__ shift) {
  int c = blockIdx.x * blockDim.x + threadIdx.x;
  if (c >= INNER) return;
  float mean = sums[c] / (float)N_NODES;
  float var = sumsq[c] / (float)N_NODES - mean * mean;
  float rstd = rsqrtf(var + BN_EPS);
  float sc = gamma[c] * rstd;
  scale[c] = sc;
  shift[c] = beta[c] - mean * sc;
}

__global__ void k_fold_bias(const float* __restrict__ outW, const float* __restrict__ shift,
                            const float* __restrict__ outb, float* __restrict__ biasp) {
  int j = blockIdx.x * blockDim.x + threadIdx.x;
  if (j >= DIM) return;
  float s = 0.f;
  for (int k = 0; k < INNER; k++) s += shift[k] * outW[(size_t)k * DIM + j];
  biasp[j] = s + outb[j];
}

// ---------------- launch ----------------
extern "C" void kernel_launch(void* const* d_in, const int* in_sizes, int n_in,
                              void* d_out, int out_size, void* d_ws, size_t ws_size,
                              hipStream_t stream) {
  (void)in_sizes; (void)n_in; (void)out_size; (void)ws_size;
  const float* x     = (const float*)d_in[0];
  const int*   ei    = (const int*)d_in[1];
  const float* Ws    = (const float*)d_in[2];
  const float* bs    = (const float*)d_in[3];
  const float* gamma = (const float*)d_in[4];
  const float* beta  = (const float*)d_in[5];
  const float* outW  = (const float*)d_in[6];
  const float* outb  = (const float*)d_in[7];
  float* out = (float*)d_out;  // doubles as hp scratch for layer GEMM outputs

  char* ws = (char*)d_ws;
  size_t off = 0;
  auto alloc = [&](size_t bytes) -> void* {
    void* p = ws + off;
    off = (off + bytes + 255) & ~(size_t)255;
    return p;
  };
  // zeroed region first (single memset)
  int*   deg    = (int*)alloc(N_NODES * 4);
  int*   cursor = (int*)alloc(N_NODES * 4);
  float* sums   = (float*)alloc(INNER * 4);
  float* sumsq  = (float*)alloc(INNER * 4);
  size_t zero_bytes = off;
  float* dinv     = (float*)alloc(N_NODES * 4);
  int*   offs     = (int*)alloc((N_NODES + 1) * 4);
  int*   csr_src  = (int*)alloc(N_EDGES * 4);
  float* csr_norm = (float*)alloc(N_EDGES * 4);
  u16*   xb  = (u16*)alloc((size_t)N_NODES * DIM * 2);
  u16*   hb1 = (u16*)alloc((size_t)N_NODES * DIM * 2);
  u16*   hb2 = (u16*)alloc((size_t)N_NODES * DIM * 2);
  u16*   hb3 = (u16*)alloc((size_t)N_NODES * DIM * 2);
  u16*   WbT = (u16*)alloc((size_t)DIM * DIM * 2);
  u16*   WpT = (u16*)alloc((size_t)INNER * DIM * 2);
  float* scale = (float*)alloc(INNER * 4);
  float* shift = (float*)alloc(INNER * 4);
  float* biasp = (float*)alloc(DIM * 4);

  hipMemsetAsync(d_ws, 0, zero_bytes, stream);
  k_deg<<<(N_EDGES + 255) / 256, 256, 0, stream>>>(ei, deg);
  k_dinv<<<(N_NODES + 255) / 256, 256, 0, stream>>>(deg, dinv);
  k_scan<<<1, 1024, 0, stream>>>(deg, offs, N_NODES);
  k_fill<<<(N_EDGES + 255) / 256, 256, 0, stream>>>(ei, offs, cursor, dinv, csr_src, csr_norm);
  k_convert<<<((N_NODES * DIM / 4) + 255) / 256, 256, 0, stream>>>(x, xb, N_NODES * DIM / 4);

  u16* Abufs[4] = {xb, hb1, hb2, hb3};
  dim3 ggrid((N_NODES + BM - 1) / BM, DIM / BN);
  for (int l = 0; l < NLAYER; l++) {
    k_transpose_scale<<<(DIM * DIM + 255) / 256, 256, 0, stream>>>(
        Ws + (size_t)l * DIM * DIM, nullptr, WbT, DIM);
    const u16* Al = Abufs[l];
    gemm_bt<<<ggrid, 256, 0, stream>>>(Al, Al, Al, Al, WbT, nullptr, out, N_NODES, DIM);
    k_aggregate<<<N_NODES, 128, 0, stream>>>(out, offs, csr_src, csr_norm, dinv,
                                             bs + (size_t)l * DIM, Abufs[l + 1]);
  }
  k_bn_stats<<<dim3(4, 125), 256, 0, stream>>>(xb, hb1, hb2, hb3, sums, sumsq, 400);
  k_bn_finalize<<<INNER / 256, 256, 0, stream>>>(sums, sumsq, gamma, beta, scale, shift);
  k_transpose_scale<<<(INNER * DIM + 255) / 256, 256, 0, stream>>>(outW, scale, WpT, INNER);
  k_fold_bias<<<2, 256, 0, stream>>>(outW, shift, outb, biasp);
  gemm_bt<<<ggrid, 256, 0, stream>>>(xb, hb1, hb2, hb3, WpT, biasp, out, N_NODES, INNER);
}

// Round 2
// 1092.734 us; speedup vs baseline: 1.3712x; 1.3712x over previous
//
#include <hip/hip_runtime.h>
#include <math.h>

#define N_NODES 50000
#define N_EDGES 400000
#define DIM 512
#define NLAYER 3
#define INNER 2048
#define BN_EPS 1e-5f
#define MPAD 50048   // N_NODES rounded up to BM multiple (slack rows for global_load_lds)

typedef unsigned short u16;
typedef unsigned int u32;

typedef __attribute__((ext_vector_type(8))) short bf16x8;
typedef __attribute__((ext_vector_type(4))) float f32x4;

__device__ __forceinline__ u16 f2bf(float f) {
  union { float f; u32 u; } v; v.f = f;
  u32 u = v.u;
  u32 r = (u + 0x7FFFu + ((u >> 16) & 1u)) >> 16;  // RNE
  return (u16)r;
}
__device__ __forceinline__ float bf2f(u16 h) {
  union { u32 u; float f; } v; v.u = ((u32)h) << 16; return v.f;
}

#define GLOAD_LDS16(g, l)                                                       \
  __builtin_amdgcn_global_load_lds(                                             \
      (const __attribute__((address_space(1))) u32*)(g),                        \
      (__attribute__((address_space(3))) u32*)(l), 16, 0, 0)

// ---------------- graph prep ----------------

__global__ void k_deg(const int* __restrict__ ei, int* __restrict__ deg) {
  int e = blockIdx.x * blockDim.x + threadIdx.x;
  if (e < N_EDGES) atomicAdd(&deg[ei[N_EDGES + e]], 1);
}

__global__ void k_dinv(const int* __restrict__ deg, float* __restrict__ dinv) {
  int i = blockIdx.x * blockDim.x + threadIdx.x;
  if (i < N_NODES) dinv[i] = rsqrtf((float)(deg[i] + 1));
}

__global__ __launch_bounds__(1024) void k_scan(const int* __restrict__ deg,
                                               int* __restrict__ offs, int n) {
  __shared__ int wsum[16];
  __shared__ int carry;
  int tid = threadIdx.x;
  int lane = tid & 63, wv = tid >> 6;
  if (tid == 0) carry = 0;
  __syncthreads();
  for (int base = 0; base < n; base += 1024) {
    int i = base + tid;
    int v = (i < n) ? deg[i] : 0;
    int x = v;
#pragma unroll
    for (int d = 1; d < 64; d <<= 1) {
      int y = __shfl_up(x, d, 64);
      if (lane >= d) x += y;
    }
    if (lane == 63) wsum[wv] = x;
    __syncthreads();
    if (wv == 0) {
      int w = (lane < 16) ? wsum[lane] : 0;
#pragma unroll
      for (int d = 1; d < 16; d <<= 1) {
        int y = __shfl_up(w, d, 64);
        if (lane >= d) w += y;
      }
      if (lane < 16) wsum[lane] = w;
    }
    __syncthreads();
    int prev = carry + (wv ? wsum[wv - 1] : 0);
    if (i < n) offs[i] = prev + x - v;
    int total = wsum[15];
    __syncthreads();
    if (tid == 0) carry += total;
    __syncthreads();
  }
  if (tid == 0) offs[n] = carry;
}

__global__ void k_fill(const int* __restrict__ ei, const int* __restrict__ offs,
                       int* __restrict__ cursor, const float* __restrict__ dinv,
                       int* __restrict__ csr_src, float* __restrict__ csr_norm) {
  int e = blockIdx.x * blockDim.x + threadIdx.x;
  if (e >= N_EDGES) return;
  int s = ei[e];
  int d = ei[N_EDGES + e];
  int p = atomicAdd(&cursor[d], 1);
  int idx = offs[d] + p;
  csr_src[idx] = s;
  csr_norm[idx] = dinv[s] * dinv[d];
}

// fp32 -> bf16 elementwise (4 elems/thread)
__global__ void k_convert(const float* __restrict__ src, u16* __restrict__ dst, int n4) {
  int i = blockIdx.x * blockDim.x + threadIdx.x;
  if (i >= n4) return;
  float4 v = ((const float4*)src)[i];
  uint2 o;
  o.x = (u32)f2bf(v.x) | ((u32)f2bf(v.y) << 16);
  o.y = (u32)f2bf(v.z) | ((u32)f2bf(v.w) << 16);
  ((uint2*)dst)[i] = o;
}

// W [K,512] fp32 -> WT [512,K] bf16, optional per-k scale
__global__ void k_transpose_scale(const float* __restrict__ W, const float* __restrict__ scale,
                                  u16* __restrict__ WT, int K) {
  int t = blockIdx.x * blockDim.x + threadIdx.x;
  if (t >= K * DIM) return;
  int k = t >> 9;
  int j = t & 511;
  float v = W[t];
  if (scale) v *= scale[k];
  WT[(size_t)j * K + k] = f2bf(v);
}

// ---------------- GEMM: C[M,512] = A[M,K] @ Bt[512,K]^T, bf16 in
// m97-style: unpadded LDS, global_load_lds width-16 staging.
// A buffers MUST have MPAD rows (slack) — staging does not bounds-check.
// Cf!=null -> fp32 out (+bias); else bf16 out to Cb.
#define BM 128
#define BN 128
#define BK 32

__global__ __launch_bounds__(256) void gemm_bt(
    const u16* __restrict__ A0, const u16* __restrict__ A1,
    const u16* __restrict__ A2, const u16* __restrict__ A3,
    const u16* __restrict__ Bt, const float* __restrict__ bias,
    float* __restrict__ Cf, u16* __restrict__ Cb, int M, int K) {
  __shared__ __align__(16) u16 As[BM * BK];
  __shared__ __align__(16) u16 Bs[BN * BK];
  int tid = threadIdx.x;
  int n0 = blockIdx.x * BN;   // n fast -> concurrent blocks share A panel in L2/L3
  int m0 = blockIdx.y * BM;
  int wave = tid >> 6, lane = tid & 63;
  int wm = (wave & 1) * 64, wn = (wave >> 1) * 64;
  int lr = lane & 15;  // row within 16
  int lq = lane >> 4;  // quad

  int ric = lane >> 2;       // row in 16-row chunk
  int seg = (lane & 3) * 8;  // 8 u16 = 16B segment within 64B row

  f32x4 acc[4][4];
#pragma unroll
  for (int i = 0; i < 4; i++)
#pragma unroll
    for (int j = 0; j < 4; j++) acc[i][j] = (f32x4){0.f, 0.f, 0.f, 0.f};

  for (int k0 = 0; k0 < K; k0 += BK) {
    int b = k0 >> 9;
    int kcol = k0 & 511;
    const u16* Abase = (b == 0) ? A0 : (b == 1) ? A1 : (b == 2) ? A2 : A3;
    // A tile: 128 rows x 32 k u16 = 8KB = 8 chunks of 1KB (16 rows each).
    // wave w stages A chunks 2w,2w+1 and B chunks 2w,2w+1. No divergence.
#pragma unroll
    for (int c = 0; c < 2; c++) {
      int chunk = wave * 2 + c;
      int arow = chunk * 16 + ric;
      GLOAD_LDS16(Abase + (size_t)(m0 + arow) * DIM + kcol + seg, &As[chunk * 512]);
      GLOAD_LDS16(Bt + (size_t)(n0 + arow) * K + k0 + seg, &Bs[chunk * 512]);
    }
    __syncthreads();
    bf16x8 af[4], bfr[4];
#pragma unroll
    for (int i = 0; i < 4; i++)
      af[i] = *(const bf16x8*)(&As[(wm + i * 16 + lr) * BK + lq * 8]);
#pragma unroll
    for (int j = 0; j < 4; j++)
      bfr[j] = *(const bf16x8*)(&Bs[(wn + j * 16 + lr) * BK + lq * 8]);
#pragma unroll
    for (int i = 0; i < 4; i++)
#pragma unroll
      for (int j = 0; j < 4; j++)
        acc[i][j] = __builtin_amdgcn_mfma_f32_16x16x32_bf16(af[i], bfr[j], acc[i][j], 0, 0, 0);
    __syncthreads();
  }
  // epilogue: D[row][col], col = lane&15, row = quad*4 + reg
#pragma unroll
  for (int i = 0; i < 4; i++) {
    int row_b = m0 + wm + i * 16 + lq * 4;
#pragma unroll
    for (int j = 0; j < 4; j++) {
      int col = n0 + wn + j * 16 + lr;
      float bv = bias ? bias[col] : 0.f;
#pragma unroll
      for (int r = 0; r < 4; r++) {
        int row = row_b + r;
        if (row < M) {
          if (Cf) Cf[(size_t)row * DIM + col] = acc[i][j][r] + bv;
          else    Cb[(size_t)row * DIM + col] = f2bf(acc[i][j][r]);
        }
      }
    }
  }
}

// ---------------- aggregation: per dst node, no atomics, bf16 h in ----------------
__global__ __launch_bounds__(128) void k_aggregate(
    const u16* __restrict__ hp, const int* __restrict__ offs,
    const int* __restrict__ csr_src, const float* __restrict__ csr_norm,
    const float* __restrict__ dinv, const float* __restrict__ b,
    u16* __restrict__ hb_out) {
  int v = blockIdx.x;
  int c4 = threadIdx.x * 4;
  float4 acc = {0.f, 0.f, 0.f, 0.f};
  int e0 = offs[v], e1 = offs[v + 1];
  for (int e = e0; e < e1; e++) {
    int s = csr_src[e];
    float w = csr_norm[e];
    uint2 hv = *(const uint2*)(hp + (size_t)s * DIM + c4);
    acc.x += w * bf2f((u16)(hv.x & 0xffffu));
    acc.y += w * bf2f((u16)(hv.x >> 16));
    acc.z += w * bf2f((u16)(hv.y & 0xffffu));
    acc.w += w * bf2f((u16)(hv.y >> 16));
  }
  float di = dinv[v];
  float w2 = di * di;
  uint2 hv = *(const uint2*)(hp + (size_t)v * DIM + c4);
  float4 bb = *(const float4*)(b + c4);
  acc.x += w2 * bf2f((u16)(hv.x & 0xffffu)) + bb.x;
  acc.y += w2 * bf2f((u16)(hv.x >> 16)) + bb.y;
  acc.z += w2 * bf2f((u16)(hv.y & 0xffffu)) + bb.z;
  acc.w += w2 * bf2f((u16)(hv.y >> 16)) + bb.w;
  // exact GELU
  acc.x = 0.5f * acc.x * (1.f + erff(acc.x * 0.70710678118654752f));
  acc.y = 0.5f * acc.y * (1.f + erff(acc.y * 0.70710678118654752f));
  acc.z = 0.5f * acc.z * (1.f + erff(acc.z * 0.70710678118654752f));
  acc.w = 0.5f * acc.w * (1.f + erff(acc.w * 0.70710678118654752f));
  uint2 o;
  o.x = (u32)f2bf(acc.x) | ((u32)f2bf(acc.y) << 16);
  o.y = (u32)f2bf(acc.z) | ((u32)f2bf(acc.w) << 16);
  *(uint2*)(hb_out + (size_t)v * DIM + c4) = o;
}

// ---------------- BN stats ----------------
__global__ void k_bn_stats(const u16* __restrict__ b0, const u16* __restrict__ b1,
                           const u16* __restrict__ b2, const u16* __restrict__ b3,
                           float* __restrict__ sums, float* __restrict__ sumsq,
                           int rows_per) {
  const u16* buf = (blockIdx.x == 0) ? b0 : (blockIdx.x == 1) ? b1 : (blockIdx.x == 2) ? b2 : b3;
  int c = threadIdx.x * 2;
  int col = blockIdx.x * DIM + c;
  int r0 = blockIdx.y * rows_per;
  int r1 = min(N_NODES, r0 + rows_per);
  float s0 = 0.f, ss0 = 0.f, s1 = 0.f, ss1 = 0.f;
  for (int r = r0; r < r1; r++) {
    u32 u = *(const u32*)(buf + (size_t)r * DIM + c);
    float x0 = bf2f((u16)(u & 0xffffu));
    float x1 = bf2f((u16)(u >> 16));
    s0 += x0; ss0 += x0 * x0;
    s1 += x1; ss1 += x1 * x1;
  }
  atomicAdd(&sums[col], s0);
  atomicAdd(&sumsq[col], ss0);
  atomicAdd(&sums[col + 1], s1);
  atomicAdd(&sumsq[col + 1], ss1);
}

__global__ void k_bn_finalize(const float* __restrict__ sums, const float* __restrict__ sumsq,
                              const float* __restrict__ gamma, const float* __restrict__ beta,
                              float* __restrict__ scale, float* __restrict__ shift) {
  int c = blockIdx.x * blockDim.x + threadIdx.x;
  if (c >= INNER) return;
  float mean = sums[c] / (float)N_NODES;
  float var = sumsq[c] / (float)N_NODES - mean * mean;
  float rstd = rsqrtf(var + BN_EPS);
  float sc = gamma[c] * rstd;
  scale[c] = sc;
  shift[c] = beta[c] - mean * sc;
}

__global__ void k_fold_bias(const float* __restrict__ outW, const float* __restrict__ shift,
                            const float* __restrict__ outb, float* __restrict__ biasp) {
  int j = blockIdx.x * blockDim.x + threadIdx.x;
  if (j >= DIM) return;
  float s = 0.f;
  for (int k = 0; k < INNER; k++) s += shift[k] * outW[(size_t)k * DIM + j];
  biasp[j] = s + outb[j];
}

// ---------------- launch ----------------
extern "C" void kernel_launch(void* const* d_in, const int* in_sizes, int n_in,
                              void* d_out, int out_size, void* d_ws, size_t ws_size,
                              hipStream_t stream) {
  (void)in_sizes; (void)n_in; (void)out_size; (void)ws_size;
  const float* x     = (const float*)d_in[0];
  const int*   ei    = (const int*)d_in[1];
  const float* Ws    = (const float*)d_in[2];
  const float* bs    = (const float*)d_in[3];
  const float* gamma = (const float*)d_in[4];
  const float* beta  = (const float*)d_in[5];
  const float* outW  = (const float*)d_in[6];
  const float* outb  = (const float*)d_in[7];
  float* out = (float*)d_out;
  u16*   hp  = (u16*)d_out;  // bf16 h scratch lives in d_out until the final GEMM

  char* ws = (char*)d_ws;
  size_t off = 0;
  auto alloc = [&](size_t bytes) -> void* {
    void* p = ws + off;
    off = (off + bytes + 255) & ~(size_t)255;
    return p;
  };
  // zeroed region first (single memset)
  int*   deg    = (int*)alloc(N_NODES * 4);
  int*   cursor = (int*)alloc(N_NODES * 4);
  float* sums   = (float*)alloc(INNER * 4);
  float* sumsq  = (float*)alloc(INNER * 4);
  size_t zero_bytes = off;
  float* dinv     = (float*)alloc(N_NODES * 4);
  int*   offs     = (int*)alloc((N_NODES + 1) * 4);
  int*   csr_src  = (int*)alloc(N_EDGES * 4);
  float* csr_norm = (float*)alloc(N_EDGES * 4);
  u16*   xb  = (u16*)alloc((size_t)MPAD * DIM * 2);  // MPAD rows: gemm staging slack
  u16*   hb1 = (u16*)alloc((size_t)MPAD * DIM * 2);
  u16*   hb2 = (u16*)alloc((size_t)MPAD * DIM * 2);
  u16*   hb3 = (u16*)alloc((size_t)MPAD * DIM * 2);
  u16*   WbT = (u16*)alloc((size_t)DIM * DIM * 2);
  u16*   WpT = (u16*)alloc((size_t)INNER * DIM * 2);
  float* scale = (float*)alloc(INNER * 4);
  float* shift = (float*)alloc(INNER * 4);
  float* biasp = (float*)alloc(DIM * 4);

  hipMemsetAsync(d_ws, 0, zero_bytes, stream);
  k_deg<<<(N_EDGES + 255) / 256, 256, 0, stream>>>(ei, deg);
  k_dinv<<<(N_NODES + 255) / 256, 256, 0, stream>>>(deg, dinv);
  k_scan<<<1, 1024, 0, stream>>>(deg, offs, N_NODES);
  k_fill<<<(N_EDGES + 255) / 256, 256, 0, stream>>>(ei, offs, cursor, dinv, csr_src, csr_norm);
  k_convert<<<((N_NODES * DIM / 4) + 255) / 256, 256, 0, stream>>>(x, xb, N_NODES * DIM / 4);

  u16* Abufs[4] = {xb, hb1, hb2, hb3};
  dim3 ggrid(DIM / BN, (N_NODES + BM - 1) / BM);  // n fast for A-panel L2 sharing
  for (int l = 0; l < NLAYER; l++) {
    k_transpose_scale<<<(DIM * DIM + 255) / 256, 256, 0, stream>>>(
        Ws + (size_t)l * DIM * DIM, nullptr, WbT, DIM);
    const u16* Al = Abufs[l];
    gemm_bt<<<ggrid, 256, 0, stream>>>(Al, Al, Al, Al, WbT, nullptr,
                                       nullptr, hp, N_NODES, DIM);
    k_aggregate<<<N_NODES, 128, 0, stream>>>(hp, offs, csr_src, csr_norm, dinv,
                                             bs + (size_t)l * DIM, Abufs[l + 1]);
  }
  k_bn_stats<<<dim3(4, 125), 256, 0, stream>>>(xb, hb1, hb2, hb3, sums, sumsq, 400);
  k_bn_finalize<<<INNER / 256, 256, 0, stream>>>(sums, sumsq, gamma, beta, scale, shift);
  k_transpose_scale<<<(INNER * DIM + 255) / 256, 256, 0, stream>>>(outW, scale, WpT, INNER);
  k_fold_bias<<<2, 256, 0, stream>>>(outW, shift, outb, biasp);
  gemm_bt<<<ggrid, 256, 0, stream>>>(xb, hb1, hb2, hb3, WpT, biasp,
                                     out, nullptr, N_NODES, INNER);
}